// Round 7
// baseline (364.347 us; speedup 1.0000x reference)
//
#include <hip/hip_runtime.h>

typedef short bfrag8 __attribute__((ext_vector_type(8)));
typedef float f32x4 __attribute__((ext_vector_type(4)));
typedef unsigned int uint4v __attribute__((ext_vector_type(4)));

// ---------- helpers ----------
__device__ __forceinline__ unsigned short f2bf(float f) {
    unsigned u = __float_as_uint(f);
    u += 0x7fffu + ((u >> 16) & 1u);   // round-to-nearest-even
    return (unsigned short)(u >> 16);
}
__device__ __forceinline__ float bf2f(unsigned short s) {
    return __uint_as_float((unsigned)s << 16);
}

// ---------- zero fill ----------
__global__ __launch_bounds__(256) void zero_i32(int* __restrict__ p, int n) {
    int i = (int)(blockIdx.x * 256u + threadIdx.x);
    int stride = gridDim.x * 256;
    for (; i < n; i += stride) p[i] = 0;
}

// ---------- conversions / weight packing ----------
__global__ __launch_bounds__(256) void cvt_f32_bf16(const float* __restrict__ in,
                                                    unsigned short* __restrict__ out, size_t n) {
    size_t i = (blockIdx.x * 256llu + threadIdx.x) * 4;
    size_t stride = (size_t)gridDim.x * 1024llu;
    for (; i < n; i += stride) {
        float4 v = *(const float4*)(in + i);
        out[i + 0] = f2bf(v.x);
        out[i + 1] = f2bf(v.y);
        out[i + 2] = f2bf(v.z);
        out[i + 3] = f2bf(v.w);
    }
}

// W1[128][512] -> frag-ready bf16: idx = (((h*4+s)*4+c)*64+l)*8+e
__global__ __launch_bounds__(256) void prep_w1(const float* __restrict__ W1,
                                               unsigned short* __restrict__ out) {
    int i = (int)(blockIdx.x * 256u + threadIdx.x);
    if (i >= 8 * 4 * 4 * 64 * 8) return;
    int e = i & 7, l = (i >> 3) & 63, c = (i >> 9) & 3, s = (i >> 11) & 3, h = i >> 13;
    int k = s * 32 + (l >> 4) * 8 + e;
    int col = h * 64 + c * 16 + (l & 15);
    out[i] = f2bf(W1[k * 512 + col]);
}

// W2[512][64] -> frag-ready bf16: idx = ((s*4+c)*64+l)*8+e  (s = 0..15)
__global__ __launch_bounds__(256) void prep_w2(const float* __restrict__ W2,
                                               unsigned short* __restrict__ out) {
    int i = (int)(blockIdx.x * 256u + threadIdx.x);
    if (i >= 16 * 4 * 64 * 8) return;
    int e = i & 7, l = (i >> 3) & 63, c = (i >> 9) & 3, s = i >> 11;
    int k = s * 32 + (l >> 4) * 8 + e;
    int col = c * 16 + (l & 15);
    out[i] = f2bf(W2[k * 64 + col]);
}

// ---------- CSR build ----------
__global__ __launch_bounds__(256) void hist_kernel(const int* __restrict__ ei,
                                                   int* __restrict__ cnt, int E, int N) {
    int t = (int)(blockIdx.x * 256u + threadIdx.x);
    if (t >= E + N) return;
    int dst = (t < E) ? ei[E + t] : t - E;
    atomicAdd(cnt + dst, 1);
}

#define SCAN_BLK 2048
__global__ __launch_bounds__(256) void scan1(const int* __restrict__ cnt,
                                             int* __restrict__ rs,
                                             int* __restrict__ bsum, int N) {
    __shared__ int lds[256];
    int base = blockIdx.x * SCAN_BLK;
    int vals[8];
    int tsum = 0;
    int idx0 = base + threadIdx.x * 8;
#pragma unroll
    for (int j = 0; j < 8; ++j) {
        int i = idx0 + j;
        int v = (i < N) ? cnt[i] : 0;
        vals[j] = tsum;
        tsum += v;
    }
    lds[threadIdx.x] = tsum;
    __syncthreads();
    for (int off = 1; off < 256; off <<= 1) {
        int v = lds[threadIdx.x];
        int u = (threadIdx.x >= (unsigned)off) ? lds[threadIdx.x - off] : 0;
        __syncthreads();
        lds[threadIdx.x] = v + u;
        __syncthreads();
    }
    int texcl = (threadIdx.x == 0) ? 0 : lds[threadIdx.x - 1];
#pragma unroll
    for (int j = 0; j < 8; ++j) {
        int i = idx0 + j;
        if (i < N) rs[i] = texcl + vals[j];
    }
    if (threadIdx.x == 255) bsum[blockIdx.x] = lds[255];
}

__global__ void scan2(int* __restrict__ bsum, int* __restrict__ rs, int nb, int N) {
    if (threadIdx.x == 0 && blockIdx.x == 0) {
        int run = 0;
        for (int b = 0; b < nb; ++b) { int t = bsum[b]; bsum[b] = run; run += t; }
        rs[N] = run;
    }
}

__global__ __launch_bounds__(256) void scan3(int* __restrict__ rs,
                                             const int* __restrict__ bsum, int N) {
    int i = (int)(blockIdx.x * 256u + threadIdx.x);
    if (i < N) rs[i] += bsum[i / SCAN_BLK];
}

__global__ __launch_bounds__(256) void scatter_kernel(const int* __restrict__ ei,
                                                      const int* __restrict__ rs,
                                                      int* __restrict__ cur,
                                                      int* __restrict__ csrc, int E, int N) {
    int t = (int)(blockIdx.x * 256u + threadIdx.x);
    if (t >= E + N) return;
    int src, dst;
    if (t < E) { src = ei[t]; dst = ei[E + t]; } else { src = dst = t - E; }
    int pos = rs[dst] + atomicAdd(cur + dst, 1);
    csrc[pos] = src;
}

// ---------- graph-range build (batch is sorted) ----------
__global__ __launch_bounds__(256) void gstart_build(const int* __restrict__ batch,
                                                    int* __restrict__ gstart, int N, int G) {
    int i = (int)(blockIdx.x * 256u + threadIdx.x);
    if (i > N) return;
    if (i == N) {
        int p = batch[N - 1];
        for (int g = p + 1; g <= G; ++g) gstart[g] = N;
    } else {
        int b = batch[i];
        int p = (i == 0) ? -1 : batch[i - 1];
        for (int g = p + 1; g <= b; ++g) gstart[g] = i;
    }
}

// ---------- MFMA GEMM L1: Cbf[M,ldc] cols [cb*64, cb*64+64) = A[M,128] @ Bfrag[cb] ----------
__global__ __launch_bounds__(256) void gemm_l1(const unsigned short* __restrict__ A,
                                               const unsigned short* __restrict__ Bfrag,
                                               unsigned short* __restrict__ Cbf,
                                               int M, int ldc, int asStride,
                                               const float* __restrict__ avs,
                                               const float* __restrict__ avd,
                                               float* __restrict__ as_,
                                               float* __restrict__ ad_) {
    const int lane = threadIdx.x & 63;
    const int wave = threadIdx.x >> 6;
    const int l15 = lane & 15, l16 = lane >> 4;
    const int cb = blockIdx.y;
    const long rowBase = (long)blockIdx.x * 128 + wave * 32;

    bfrag8 bf[4][4];
    const bfrag8* bp = (const bfrag8*)(Bfrag + (size_t)cb * 8192);
#pragma unroll
    for (int s = 0; s < 4; ++s)
#pragma unroll
        for (int c = 0; c < 4; ++c)
            bf[s][c] = bp[(s * 4 + c) * 64 + lane];

    f32x4 acc[2][4];
#pragma unroll
    for (int r = 0; r < 2; ++r)
#pragma unroll
        for (int c = 0; c < 4; ++c)
#pragma unroll
            for (int e = 0; e < 4; ++e) acc[r][c][e] = 0.f;

    long r0 = rowBase + l15;        if (r0 > M - 1) r0 = M - 1;
    long r1 = rowBase + 16 + l15;   if (r1 > M - 1) r1 = M - 1;
    const unsigned short* a0p = A + r0 * 128 + l16 * 8;
    const unsigned short* a1p = A + r1 * 128 + l16 * 8;

#pragma unroll
    for (int s = 0; s < 4; ++s) {
        bfrag8 a0 = *(const bfrag8*)(a0p + s * 32);
        bfrag8 a1 = *(const bfrag8*)(a1p + s * 32);
#pragma unroll
        for (int c = 0; c < 4; ++c) {
            acc[0][c] = __builtin_amdgcn_mfma_f32_16x16x32_bf16(a0, bf[s][c], acc[0][c], 0, 0, 0);
            acc[1][c] = __builtin_amdgcn_mfma_f32_16x16x32_bf16(a1, bf[s][c], acc[1][c], 0, 0, 0);
        }
    }

    float avsv[4], avdv[4];
#pragma unroll
    for (int c = 0; c < 4; ++c) {
        avsv[c] = avs[cb * 64 + c * 16 + l15];
        avdv[c] = avd[cb * 64 + c * 16 + l15];
    }

#pragma unroll
    for (int r = 0; r < 2; ++r) {
#pragma unroll
        for (int reg = 0; reg < 4; ++reg) {
            long row = rowBase + r * 16 + l16 * 4 + reg;
            bool ok = row < M;
            float ps = 0.f, pd = 0.f;
#pragma unroll
            for (int c = 0; c < 4; ++c) {
                float v = acc[r][c][reg];
                if (ok) Cbf[row * ldc + cb * 64 + c * 16 + l15] = f2bf(v);
                ps += v * avsv[c];
                pd += v * avdv[c];
            }
#pragma unroll
            for (int off = 1; off < 16; off <<= 1) {
                ps += __shfl_xor(ps, off);
                pd += __shfl_xor(pd, off);
            }
            if (l15 == 0 && ok) {
                as_[row * asStride + cb] = ps;
                ad_[row * asStride + cb] = pd;
            }
        }
    }
}

// ---------- old-style accumulate GEMM (fallback path, KS=2, C64) ----------
template<bool ACC, bool WF32, bool WBF16, bool ATTN>
__global__ __launch_bounds__(256) void gemm_acc(const unsigned short* __restrict__ A,
                                                const unsigned short* __restrict__ Bfrag,
                                                float* __restrict__ Cf32,
                                                unsigned short* __restrict__ Cbf,
                                                int M,
                                                const float* __restrict__ avs,
                                                const float* __restrict__ avd,
                                                float* __restrict__ as_,
                                                float* __restrict__ ad_) {
    const int lane = threadIdx.x & 63;
    const int wave = threadIdx.x >> 6;
    const int l15 = lane & 15, l16 = lane >> 4;
    const long rowBase = (long)blockIdx.x * 128 + wave * 32;

    bfrag8 bf[2][4];
    const bfrag8* bp = (const bfrag8*)Bfrag;
#pragma unroll
    for (int s = 0; s < 2; ++s)
#pragma unroll
        for (int c = 0; c < 4; ++c)
            bf[s][c] = bp[(s * 4 + c) * 64 + lane];

    f32x4 acc[2][4];
#pragma unroll
    for (int r = 0; r < 2; ++r)
#pragma unroll
        for (int c = 0; c < 4; ++c)
#pragma unroll
            for (int e = 0; e < 4; ++e) acc[r][c][e] = 0.f;

    long r0 = rowBase + l15;        if (r0 > M - 1) r0 = M - 1;
    long r1 = rowBase + 16 + l15;   if (r1 > M - 1) r1 = M - 1;
    const unsigned short* a0p = A + r0 * 64 + l16 * 8;
    const unsigned short* a1p = A + r1 * 64 + l16 * 8;

#pragma unroll
    for (int s = 0; s < 2; ++s) {
        bfrag8 a0 = *(const bfrag8*)(a0p + s * 32);
        bfrag8 a1 = *(const bfrag8*)(a1p + s * 32);
#pragma unroll
        for (int c = 0; c < 4; ++c) {
            acc[0][c] = __builtin_amdgcn_mfma_f32_16x16x32_bf16(a0, bf[s][c], acc[0][c], 0, 0, 0);
            acc[1][c] = __builtin_amdgcn_mfma_f32_16x16x32_bf16(a1, bf[s][c], acc[1][c], 0, 0, 0);
        }
    }

    float avsv[4], avdv[4];
    if (ATTN) {
#pragma unroll
        for (int c = 0; c < 4; ++c) {
            avsv[c] = avs[c * 16 + l15];
            avdv[c] = avd[c * 16 + l15];
        }
    }

#pragma unroll
    for (int r = 0; r < 2; ++r) {
#pragma unroll
        for (int reg = 0; reg < 4; ++reg) {
            long row = rowBase + r * 16 + l16 * 4 + reg;
            bool ok = row < M;
            float ps = 0.f, pd = 0.f;
#pragma unroll
            for (int c = 0; c < 4; ++c) {
                float v = acc[r][c][reg];
                long idx = row * 64 + c * 16 + l15;
                if (ACC && ok) v += Cf32[idx];
                if (WF32 && ok) Cf32[idx] = v;
                if (WBF16 && ok) Cbf[idx] = f2bf(v);
                if (ATTN) { ps += v * avsv[c]; pd += v * avdv[c]; }
            }
            if (ATTN) {
#pragma unroll
                for (int off = 1; off < 16; off <<= 1) {
                    ps += __shfl_xor(ps, off);
                    pd += __shfl_xor(pd, off);
                }
                if (l15 == 0 && ok) { as_[row] = ps; ad_[row] = pd; }
            }
        }
    }
}

// ---------- FUSED: gather8 (64 nodes -> LDS, swizzled) + [64x512]@W2 MFMA + attn2 dots ----------
__global__ __launch_bounds__(256) void gat_fused(const int* __restrict__ csrc,
                                                 const int* __restrict__ rs,
                                                 const float* __restrict__ as_,  // [N][8]
                                                 const float* __restrict__ ad_,  // [N][8]
                                                 const unsigned short* __restrict__ h, // [N][512]
                                                 const float* __restrict__ bias,      // [512]
                                                 const unsigned short* __restrict__ Bfrag, // W2 frags
                                                 unsigned short* __restrict__ h2bf,   // [N][64]
                                                 const float* __restrict__ avs,
                                                 const float* __restrict__ avd,
                                                 float* __restrict__ as2,
                                                 float* __restrict__ ad2, int N) {
    __shared__ unsigned char ldsb[64 * 1024];
    const int tid = threadIdx.x;
    const int lane = tid & 63;
    const int wave = tid >> 6;
    const unsigned* hu = (const unsigned*)h;

    // ---- phase A: gather 64 node rows into LDS (bf16, XOR-swizzled) ----
    for (int t = wave; t < 64; t += 4) {
        int node = blockIdx.x * 64 + t;
        uint4v o = {0u, 0u, 0u, 0u};
        if (node < N) {
            int myh = lane >> 3;
            int s0 = rs[node], s1 = rs[node + 1];
            float adn = ad_[(size_t)node * 8 + myh];
            float den = 0.f;
            float2 acc[4] = {};
            int k = s0;
            for (; k + 4 <= s1; k += 4) {
                int i0 = csrc[k], i1 = csrc[k + 1], i2 = csrc[k + 2], i3 = csrc[k + 3];
                float a0 = as_[(size_t)i0 * 8 + myh] + adn;
                float a1 = as_[(size_t)i1 * 8 + myh] + adn;
                float a2 = as_[(size_t)i2 * 8 + myh] + adn;
                float a3 = as_[(size_t)i3 * 8 + myh] + adn;
                a0 = a0 > 0.f ? a0 : 0.2f * a0;  a1 = a1 > 0.f ? a1 : 0.2f * a1;
                a2 = a2 > 0.f ? a2 : 0.2f * a2;  a3 = a3 > 0.f ? a3 : 0.2f * a3;
                float w0 = __expf(fminf(a0, 60.f)), w1 = __expf(fminf(a1, 60.f));
                float w2 = __expf(fminf(a2, 60.f)), w3 = __expf(fminf(a3, 60.f));
                uint4v v0 = *(const uint4v*)(hu + (size_t)i0 * 256 + lane * 4);
                uint4v v1 = *(const uint4v*)(hu + (size_t)i1 * 256 + lane * 4);
                uint4v v2 = *(const uint4v*)(hu + (size_t)i2 * 256 + lane * 4);
                uint4v v3 = *(const uint4v*)(hu + (size_t)i3 * 256 + lane * 4);
                den += (w0 + w1) + (w2 + w3);
#pragma unroll
                for (int j = 0; j < 4; ++j) {
                    acc[j].x += w0 * __uint_as_float(v0[j] << 16);
                    acc[j].y += w0 * __uint_as_float(v0[j] & 0xffff0000u);
                    acc[j].x += w1 * __uint_as_float(v1[j] << 16);
                    acc[j].y += w1 * __uint_as_float(v1[j] & 0xffff0000u);
                    acc[j].x += w2 * __uint_as_float(v2[j] << 16);
                    acc[j].y += w2 * __uint_as_float(v2[j] & 0xffff0000u);
                    acc[j].x += w3 * __uint_as_float(v3[j] << 16);
                    acc[j].y += w3 * __uint_as_float(v3[j] & 0xffff0000u);
                }
            }
            for (; k < s1; ++k) {
                int i0 = csrc[k];
                float a = as_[(size_t)i0 * 8 + myh] + adn;
                a = a > 0.f ? a : 0.2f * a;
                float w = __expf(fminf(a, 60.f));
                uint4v v0 = *(const uint4v*)(hu + (size_t)i0 * 256 + lane * 4);
                den += w;
#pragma unroll
                for (int j = 0; j < 4; ++j) {
                    acc[j].x += w * __uint_as_float(v0[j] << 16);
                    acc[j].y += w * __uint_as_float(v0[j] & 0xffff0000u);
                }
            }
            float rden = 1.f / (den + 1e-16f);
#pragma unroll
            for (int j = 0; j < 4; ++j) {
                float vlo = acc[j].x * rden + bias[lane * 8 + 2 * j];
                float vhi = acc[j].y * rden + bias[lane * 8 + 2 * j + 1];
                vlo = vlo > 0.f ? vlo : 0.f;
                vhi = vhi > 0.f ? vhi : 0.f;
                o[j] = (unsigned)f2bf(vlo) | ((unsigned)f2bf(vhi) << 16);
            }
        }
        unsigned byteoff = (unsigned)t * 1024u + (((unsigned)lane * 16u) ^ (((unsigned)(t & 7)) << 4));
        *(uint4v*)(ldsb + byteoff) = o;
    }
    __syncthreads();

    // ---- phase B: [64x512] (LDS) @ W2 -> h2[64x64] + attn2 dots ----
    const int l15 = lane & 15, l16 = lane >> 4;
    const bfrag8* bp = (const bfrag8*)Bfrag;
    const int rloc = wave * 16 + l15;

    f32x4 acc[4];
#pragma unroll
    for (int c = 0; c < 4; ++c)
#pragma unroll
        for (int e = 0; e < 4; ++e) acc[c][e] = 0.f;

    for (int s = 0; s < 16; ++s) {
        unsigned aoff = (unsigned)rloc * 1024u +
                        (((unsigned)(s * 64 + l16 * 16)) ^ (((unsigned)(rloc & 7)) << 4));
        bfrag8 a = *(const bfrag8*)(ldsb + aoff);
        bfrag8 b0 = bp[(s * 4 + 0) * 64 + lane];
        bfrag8 b1 = bp[(s * 4 + 1) * 64 + lane];
        bfrag8 b2 = bp[(s * 4 + 2) * 64 + lane];
        bfrag8 b3 = bp[(s * 4 + 3) * 64 + lane];
        acc[0] = __builtin_amdgcn_mfma_f32_16x16x32_bf16(a, b0, acc[0], 0, 0, 0);
        acc[1] = __builtin_amdgcn_mfma_f32_16x16x32_bf16(a, b1, acc[1], 0, 0, 0);
        acc[2] = __builtin_amdgcn_mfma_f32_16x16x32_bf16(a, b2, acc[2], 0, 0, 0);
        acc[3] = __builtin_amdgcn_mfma_f32_16x16x32_bf16(a, b3, acc[3], 0, 0, 0);
    }

    float avsv[4], avdv[4];
#pragma unroll
    for (int c = 0; c < 4; ++c) {
        avsv[c] = avs[c * 16 + l15];
        avdv[c] = avd[c * 16 + l15];
    }

#pragma unroll
    for (int reg = 0; reg < 4; ++reg) {
        long row = (long)blockIdx.x * 64 + wave * 16 + l16 * 4 + reg;
        bool ok = row < N;
        float ps = 0.f, pd = 0.f;
#pragma unroll
        for (int c = 0; c < 4; ++c) {
            float v = acc[c][reg];
            if (ok) h2bf[row * 64 + c * 16 + l15] = f2bf(v);
            ps += v * avsv[c];
            pd += v * avdv[c];
        }
#pragma unroll
        for (int off = 1; off < 16; off <<= 1) {
            ps += __shfl_xor(ps, off);
            pd += __shfl_xor(pd, off);
        }
        if (l15 == 0 && ok) { as2[row] = ps; ad2[row] = pd; }
    }
}

// ---------- single-head gather (64-wide) ----------
template<bool OBF>
__global__ __launch_bounds__(256) void gather1(const int* __restrict__ csrc,
                                               const int* __restrict__ rs,
                                               const float* __restrict__ as_,
                                               const float* __restrict__ ad_,
                                               const unsigned short* __restrict__ h,
                                               const float* __restrict__ bias,
                                               void* __restrict__ outp, int N) {
    int node = (int)((blockIdx.x * 256u + threadIdx.x) >> 6);
    int lane = threadIdx.x & 63;
    if (node >= N) return;
    int s0 = rs[node], s1 = rs[node + 1];
    float adn = ad_[node];
    float den = 0.f, acc = 0.f;
    int k = s0;
    for (; k + 4 <= s1; k += 4) {
        int i0 = csrc[k], i1 = csrc[k + 1], i2 = csrc[k + 2], i3 = csrc[k + 3];
        float a0 = as_[i0] + adn, a1 = as_[i1] + adn, a2 = as_[i2] + adn, a3 = as_[i3] + adn;
        a0 = a0 > 0.f ? a0 : 0.2f * a0;  a1 = a1 > 0.f ? a1 : 0.2f * a1;
        a2 = a2 > 0.f ? a2 : 0.2f * a2;  a3 = a3 > 0.f ? a3 : 0.2f * a3;
        float w0 = __expf(fminf(a0, 60.f)), w1 = __expf(fminf(a1, 60.f));
        float w2 = __expf(fminf(a2, 60.f)), w3 = __expf(fminf(a3, 60.f));
        float h0 = bf2f(h[(size_t)i0 * 64 + lane]);
        float h1 = bf2f(h[(size_t)i1 * 64 + lane]);
        float h2 = bf2f(h[(size_t)i2 * 64 + lane]);
        float h3 = bf2f(h[(size_t)i3 * 64 + lane]);
        den += (w0 + w1) + (w2 + w3);
        acc += w0 * h0;  acc += w1 * h1;  acc += w2 * h2;  acc += w3 * h3;
    }
    for (; k < s1; ++k) {
        int i0 = csrc[k];
        float a = as_[i0] + adn;
        a = a > 0.f ? a : 0.2f * a;
        float w = __expf(fminf(a, 60.f));
        den += w;
        acc += w * bf2f(h[(size_t)i0 * 64 + lane]);
    }
    float v = acc / (den + 1e-16f) + bias[lane];
    v = v > 0.f ? v : 0.f;
    if (OBF) ((unsigned short*)outp)[(size_t)node * 64 + lane] = f2bf(v);
    else     ((float*)outp)[(size_t)node * 64 + lane] = v;
}

// ---------- fused mean-pool + readout (sorted batch, one wave per graph) ----------
__global__ __launch_bounds__(256) void pool_readout(const float* __restrict__ h2,
                                                    const int* __restrict__ gstart,
                                                    const float* __restrict__ Wf,
                                                    const float* __restrict__ bf,
                                                    float* __restrict__ out, int G) {
    int g = (int)((blockIdx.x * 256u + threadIdx.x) >> 6);
    int lane = threadIdx.x & 63;
    if (g >= G) return;
    int s0 = gstart[g], s1 = gstart[g + 1];
    float acc = 0.f;
    int i = s0;
    for (; i + 2 <= s1; i += 2) {
        acc += h2[(size_t)i * 64 + lane];
        acc += h2[(size_t)(i + 1) * 64 + lane];
    }
    if (i < s1) acc += h2[(size_t)i * 64 + lane];
    float c = (float)(s1 - s0);
    c = c < 1.f ? 1.f : c;
    float v = acc / c * Wf[lane];
#pragma unroll
    for (int off = 32; off; off >>= 1) v += __shfl_xor(v, off);
    if (lane == 0) out[g] = v + bf[0];
}

extern "C" void kernel_launch(void* const* d_in, const int* in_sizes, int n_in,
                              void* d_out, int out_size, void* d_ws, size_t ws_size,
                              hipStream_t stream) {
    const float* x        = (const float*)d_in[0];
    const int*   ei       = (const int*)d_in[1];
    const int*   batch    = (const int*)d_in[2];
    const float* W1       = (const float*)d_in[3];
    const float* att_src1 = (const float*)d_in[4];
    const float* att_dst1 = (const float*)d_in[5];
    const float* b1       = (const float*)d_in[6];
    const float* W2       = (const float*)d_in[7];
    const float* att_src2 = (const float*)d_in[8];
    const float* att_dst2 = (const float*)d_in[9];
    const float* b2       = (const float*)d_in[10];
    const float* Wf       = (const float*)d_in[11];
    const float* bf       = (const float*)d_in[12];
    float* out = (float*)d_out;

    const int N = in_sizes[2];        // 100000
    const int E = in_sizes[1] / 2;    // 400000
    const int G = out_size;           // 4096

    const int nb = (N + SCAN_BLK - 1) / SCAN_BLK;
    const int nodeWaveGrid = (int)(((size_t)N * 64 + 255) / 256);
    const int edgeGrid = (E + N + 255) / 256;
    const int gemmGrid = (N + 127) / 128;

    // ---- common small buffers at the head of ws ----
    char* base = (char*)d_ws;
    size_t off = 0;
    auto alloc = [&](size_t bytes) { char* p = base + off; off += (bytes + 255) & ~255llu; return p; };
    unsigned short* wf1   = (unsigned short*)alloc(131072);
    unsigned short* wf2   = (unsigned short*)alloc(65536);
    float* as1            = (float*)alloc((size_t)N * 8 * 4);
    float* ad1            = (float*)alloc((size_t)N * 8 * 4);
    float* as2            = (float*)alloc((size_t)N * 4);
    float* ad2            = (float*)alloc((size_t)N * 4);
    int*   cnt_i          = (int*)alloc((size_t)N * 4);
    int*   rs             = (int*)alloc((size_t)(N + 1) * 4);
    int*   csrc           = (int*)alloc((size_t)(E + N) * 4);
    int*   bsum           = (int*)alloc(1024);
    int*   gstart         = (int*)alloc((size_t)(G + 1) * 4);
    unsigned short* x_bf  = (unsigned short*)alloc((size_t)N * 128 * 2);
    float* ob2            = (float*)x_bf;   // alias: x_bf dead before ob2 written
    unsigned short* h2bf  = (unsigned short*)alloc((size_t)N * 64 * 2);
    size_t commonEnd = off;

    // fused-path big buffer (h1 only; ob1 no longer materialized)
    size_t fusedNeed = commonEnd + (((size_t)N * 512 * 2 + 255) & ~255llu);
    bool fused = ws_size >= fusedNeed;

    // ---- shared prologue ----
    cvt_f32_bf16<<<2048, 256, 0, stream>>>(x, x_bf, (size_t)N * 128);
    prep_w1<<<(8 * 4 * 4 * 64 * 8) / 256, 256, 0, stream>>>(W1, wf1);
    prep_w2<<<(16 * 4 * 64 * 8) / 256, 256, 0, stream>>>(W2, wf2);

    zero_i32<<<512, 256, 0, stream>>>(cnt_i, N);
    hist_kernel<<<edgeGrid, 256, 0, stream>>>(ei, cnt_i, E, N);
    scan1<<<nb, 256, 0, stream>>>(cnt_i, rs, bsum, N);
    scan2<<<1, 1, 0, stream>>>(bsum, rs, nb, N);
    scan3<<<(N + 255) / 256, 256, 0, stream>>>(rs, bsum, N);
    zero_i32<<<512, 256, 0, stream>>>(cnt_i, N);
    scatter_kernel<<<edgeGrid, 256, 0, stream>>>(ei, rs, cnt_i, csrc, E, N);
    gstart_build<<<(N + 256) / 256, 256, 0, stream>>>(batch, gstart, N, G);

    if (fused) {
        unsigned short* h1_bf = (unsigned short*)alloc((size_t)N * 512 * 2);

        // layer 1: one GEMM for all heads
        dim3 g1(gemmGrid, 8);
        gemm_l1<<<g1, 256, 0, stream>>>(x_bf, wf1, h1_bf, N, 512, 8,
                                        att_src1, att_dst1, as1, ad1);
        // fused: gather all heads -> LDS -> W2 MFMA -> h2bf + attn2 dots
        gat_fused<<<(N + 63) / 64, 256, 0, stream>>>(csrc, rs, as1, ad1, h1_bf, b1,
                                                     wf2, h2bf, att_src2, att_dst2,
                                                     as2, ad2, N);
        gather1<false><<<nodeWaveGrid, 256, 0, stream>>>(csrc, rs, as2, ad2, h2bf, b2, ob2, N);
    } else {
        // fallback: per-head streaming (round-4 structure)
        unsigned short* hb_bf = (unsigned short*)alloc((size_t)N * 64 * 2);
        unsigned short* ob_bf = (unsigned short*)alloc((size_t)N * 64 * 2);
        float* h2acc          = (float*)alloc((size_t)N * 64 * 4);

        for (int h = 0; h < 8; ++h) {
            dim3 g1(gemmGrid, 1);
            gemm_l1<<<g1, 256, 0, stream>>>(x_bf, wf1 + (size_t)h * 8192, hb_bf, N, 64, 1,
                                            att_src1 + h * 64, att_dst1 + h * 64, as1, ad1);
            gather1<true><<<nodeWaveGrid, 256, 0, stream>>>(csrc, rs, as1, ad1, hb_bf, b1 + h * 64, ob_bf, N);
            if (h == 0) {
                gemm_acc<false, true, false, false><<<gemmGrid, 256, 0, stream>>>(
                    ob_bf, wf2, h2acc, nullptr, N, nullptr, nullptr, nullptr, nullptr);
            } else if (h < 7) {
                gemm_acc<true, true, false, false><<<gemmGrid, 256, 0, stream>>>(
                    ob_bf, wf2 + (size_t)h * 4096, h2acc, nullptr, N, nullptr, nullptr, nullptr, nullptr);
            } else {
                gemm_acc<true, false, true, true><<<gemmGrid, 256, 0, stream>>>(
                    ob_bf, wf2 + (size_t)h * 4096, h2acc, h2bf, N,
                    att_src2, att_dst2, as2, ad2);
            }
        }
        gather1<false><<<nodeWaveGrid, 256, 0, stream>>>(csrc, rs, as2, ad2, h2bf, b2, ob2, N);
    }

    // ---- fused pool + readout ----
    pool_readout<<<(G * 64 + 255) / 256, 256, 0, stream>>>(ob2, gstart, Wf, bf, out, G);
}

// Round 9
// 292.694 us; speedup vs baseline: 1.2448x; 1.2448x over previous
//
#include <hip/hip_runtime.h>

typedef short bfrag8 __attribute__((ext_vector_type(8)));
typedef float f32x4 __attribute__((ext_vector_type(4)));
typedef unsigned int uint4v __attribute__((ext_vector_type(4)));

#define SCAN_BLK 2048

// ---------- helpers ----------
__device__ __forceinline__ unsigned short f2bf(float f) {
    unsigned u = __float_as_uint(f);
    u += 0x7fffu + ((u >> 16) & 1u);   // round-to-nearest-even
    return (unsigned short)(u >> 16);
}
__device__ __forceinline__ float bf2f(unsigned short s) {
    return __uint_as_float((unsigned)s << 16);
}

// ---------- K1: fused prologue ----------
// blocks [0,1024): cvt x -> x_bf          (stride loop over N*128)
// [1024,1536): zero cnt                    (512*256 = 131072 >= N)
// [1536,1792): pack W1  (256 blk * 256 thr = 65536 = 8*4*4*64*8 items)
// [1792,1920): pack W2  (128 blk * 256 thr = 32768 = 16*4*64*8 items)
// [1920,...):  gstart build + rs[N]=E+N
__global__ __launch_bounds__(256) void prologue(const float* __restrict__ x,
                                                unsigned short* __restrict__ x_bf,
                                                int* __restrict__ cnt,
                                                const float* __restrict__ W1,
                                                const float* __restrict__ W2,
                                                unsigned short* __restrict__ wf1,
                                                unsigned short* __restrict__ wf2,
                                                const int* __restrict__ batch,
                                                int* __restrict__ gstart,
                                                int* __restrict__ rs,
                                                int N, int G, int E) {
    const int b = blockIdx.x, t = threadIdx.x;
    if (b < 1024) {
        size_t n = (size_t)N * 128;
        size_t i = ((size_t)b * 256 + t) * 4;
        size_t stride = 1024llu * 256 * 4;
        for (; i < n; i += stride) {
            float4 v = *(const float4*)(x + i);
            x_bf[i + 0] = f2bf(v.x);
            x_bf[i + 1] = f2bf(v.y);
            x_bf[i + 2] = f2bf(v.z);
            x_bf[i + 3] = f2bf(v.w);
        }
    } else if (b < 1536) {
        int i = (b - 1024) * 256 + t;
        if (i < N) cnt[i] = 0;
    } else if (b < 1792) {
        int i = (b - 1536) * 256 + t;   // 65536 items
        if (i < 8 * 4 * 4 * 64 * 8) {
            int e = i & 7, l = (i >> 3) & 63, c = (i >> 9) & 3, s = (i >> 11) & 3, h = i >> 13;
            int k = s * 32 + (l >> 4) * 8 + e;
            int col = h * 64 + c * 16 + (l & 15);
            wf1[i] = f2bf(W1[k * 512 + col]);
        }
    } else if (b < 1920) {
        int i = (b - 1792) * 256 + t;   // 32768 items
        if (i < 16 * 4 * 64 * 8) {
            int e = i & 7, l = (i >> 3) & 63, c = (i >> 9) & 3, s = i >> 11;
            int k = s * 32 + (l >> 4) * 8 + e;
            int col = c * 16 + (l & 15);
            wf2[i] = f2bf(W2[k * 64 + col]);
        }
    } else {
        int i = (b - 1920) * 256 + t;
        if (i == 0) rs[N] = E + N;
        if (i > N) return;
        if (i == N) {
            int p = batch[N - 1];
            for (int g = p + 1; g <= G; ++g) gstart[g] = N;
        } else {
            int bb = batch[i];
            int p = (i == 0) ? -1 : batch[i - 1];
            for (int g = p + 1; g <= bb; ++g) gstart[g] = i;
        }
    }
}

// ---------- K2: MFMA GEMM L1 (all heads) + histogram tail blocks ----------
__global__ __launch_bounds__(256) void gemm_l1_hist(const unsigned short* __restrict__ A,
                                                    const unsigned short* __restrict__ Bfrag,
                                                    unsigned short* __restrict__ Cbf,
                                                    int M,
                                                    const float* __restrict__ avs,
                                                    const float* __restrict__ avd,
                                                    float* __restrict__ as_,
                                                    float* __restrict__ ad_,
                                                    int gemmBlocks, int rowBlocks,
                                                    const int* __restrict__ ei,
                                                    int* __restrict__ cnt, int E) {
    const int b = blockIdx.x;
    if (b >= gemmBlocks) {
        int t = (b - gemmBlocks) * 256 + threadIdx.x;
        if (t < E + M) {
            int dst = (t < E) ? ei[E + t] : t - E;
            atomicAdd(cnt + dst, 1);
        }
        return;
    }
    const int rb = b % rowBlocks;
    const int cb = b / rowBlocks;
    const int lane = threadIdx.x & 63;
    const int wave = threadIdx.x >> 6;
    const int l15 = lane & 15, l16 = lane >> 4;
    const long rowBase = (long)rb * 128 + wave * 32;

    bfrag8 bf[4][4];
    const bfrag8* bp = (const bfrag8*)(Bfrag + (size_t)cb * 8192);
#pragma unroll
    for (int s = 0; s < 4; ++s)
#pragma unroll
        for (int c = 0; c < 4; ++c)
            bf[s][c] = bp[(s * 4 + c) * 64 + lane];

    f32x4 acc[2][4];
#pragma unroll
    for (int r = 0; r < 2; ++r)
#pragma unroll
        for (int c = 0; c < 4; ++c)
#pragma unroll
            for (int e = 0; e < 4; ++e) acc[r][c][e] = 0.f;

    long r0 = rowBase + l15;        if (r0 > M - 1) r0 = M - 1;
    long r1 = rowBase + 16 + l15;   if (r1 > M - 1) r1 = M - 1;
    const unsigned short* a0p = A + r0 * 128 + l16 * 8;
    const unsigned short* a1p = A + r1 * 128 + l16 * 8;

#pragma unroll
    for (int s = 0; s < 4; ++s) {
        bfrag8 a0 = *(const bfrag8*)(a0p + s * 32);
        bfrag8 a1 = *(const bfrag8*)(a1p + s * 32);
#pragma unroll
        for (int c = 0; c < 4; ++c) {
            acc[0][c] = __builtin_amdgcn_mfma_f32_16x16x32_bf16(a0, bf[s][c], acc[0][c], 0, 0, 0);
            acc[1][c] = __builtin_amdgcn_mfma_f32_16x16x32_bf16(a1, bf[s][c], acc[1][c], 0, 0, 0);
        }
    }

    float avsv[4], avdv[4];
#pragma unroll
    for (int c = 0; c < 4; ++c) {
        avsv[c] = avs[cb * 64 + c * 16 + l15];
        avdv[c] = avd[cb * 64 + c * 16 + l15];
    }

#pragma unroll
    for (int r = 0; r < 2; ++r) {
#pragma unroll
        for (int reg = 0; reg < 4; ++reg) {
            long row = rowBase + r * 16 + l16 * 4 + reg;
            bool ok = row < M;
            float ps = 0.f, pd = 0.f;
#pragma unroll
            for (int c = 0; c < 4; ++c) {
                float v = acc[r][c][reg];
                if (ok) Cbf[row * 512 + cb * 64 + c * 16 + l15] = f2bf(v);
                ps += v * avsv[c];
                pd += v * avdv[c];
            }
#pragma unroll
            for (int off = 1; off < 16; off <<= 1) {
                ps += __shfl_xor(ps, off);
                pd += __shfl_xor(pd, off);
            }
            if (l15 == 0 && ok) {
                as_[row * 8 + cb] = ps;
                ad_[row * 8 + cb] = pd;
            }
        }
    }
}

// ---------- K3: per-chunk scan ----------
__global__ __launch_bounds__(256) void scan1(const int* __restrict__ cnt,
                                             int* __restrict__ rs,
                                             int* __restrict__ bsum, int N) {
    __shared__ int lds[256];
    int base = blockIdx.x * SCAN_BLK;
    int vals[8];
    int tsum = 0;
    int idx0 = base + threadIdx.x * 8;
#pragma unroll
    for (int j = 0; j < 8; ++j) {
        int i = idx0 + j;
        int v = (i < N) ? cnt[i] : 0;
        vals[j] = tsum;
        tsum += v;
    }
    lds[threadIdx.x] = tsum;
    __syncthreads();
    for (int off = 1; off < 256; off <<= 1) {
        int v = lds[threadIdx.x];
        int u = (threadIdx.x >= (unsigned)off) ? lds[threadIdx.x - off] : 0;
        __syncthreads();
        lds[threadIdx.x] = v + u;
        __syncthreads();
    }
    int texcl = (threadIdx.x == 0) ? 0 : lds[threadIdx.x - 1];
#pragma unroll
    for (int j = 0; j < 8; ++j) {
        int i = idx0 + j;
        if (i < N) rs[i] = texcl + vals[j];
    }
    if (threadIdx.x == 255) bsum[blockIdx.x] = lds[255];
}

// ---------- K4: scan fixup ----------
__global__ __launch_bounds__(256) void scan_fix(int* __restrict__ rs,
                                                const int* __restrict__ bsum, int N) {
    __shared__ int sprefix;
    int b = blockIdx.x;
    int i = b * 256 + threadIdx.x;
    int chunk = (b * 256) / SCAN_BLK;
    if (threadIdx.x == 0) {
        int p = 0;
        for (int k = 0; k < chunk; ++k) p += bsum[k];
        sprefix = p;
    }
    __syncthreads();
    if (i < N) rs[i] += sprefix;
}

// ---------- K5: scatter via count-down ----------
__global__ __launch_bounds__(256) void scatter_cd(const int* __restrict__ ei,
                                                  const int* __restrict__ rs,
                                                  int* __restrict__ cnt,
                                                  int* __restrict__ csrc, int E, int N) {
    int t = (int)(blockIdx.x * 256u + threadIdx.x);
    if (t >= E + N) return;
    int src, dst;
    if (t < E) { src = ei[t]; dst = ei[E + t]; } else { src = dst = t - E; }
    int pos = rs[dst] + atomicSub(cnt + dst, 1) - 1;
    csrc[pos] = src;
}

// ---------- K6: gather over all 8 heads ----------
__global__ __launch_bounds__(256) void gather8(const int* __restrict__ csrc,
                                               const int* __restrict__ rs,
                                               const float* __restrict__ as_,  // [N][8]
                                               const float* __restrict__ ad_,  // [N][8]
                                               const unsigned short* __restrict__ h, // [N][512]
                                               const float* __restrict__ bias,      // [512]
                                               unsigned short* __restrict__ outp,   // [N][512]
                                               int N) {
    int node = (int)((blockIdx.x * 256u + threadIdx.x) >> 6);
    int lane = threadIdx.x & 63;
    if (node >= N) return;
    int myh = lane >> 3;
    int s0 = rs[node], s1 = rs[node + 1];
    float adn = ad_[(size_t)node * 8 + myh];
    float den = 0.f;
    float2 acc[4] = {};
    const unsigned* hu = (const unsigned*)h;
    int k = s0;
    for (; k + 4 <= s1; k += 4) {
        int i0 = csrc[k], i1 = csrc[k + 1], i2 = csrc[k + 2], i3 = csrc[k + 3];
        float a0 = as_[(size_t)i0 * 8 + myh] + adn;
        float a1 = as_[(size_t)i1 * 8 + myh] + adn;
        float a2 = as_[(size_t)i2 * 8 + myh] + adn;
        float a3 = as_[(size_t)i3 * 8 + myh] + adn;
        a0 = a0 > 0.f ? a0 : 0.2f * a0;  a1 = a1 > 0.f ? a1 : 0.2f * a1;
        a2 = a2 > 0.f ? a2 : 0.2f * a2;  a3 = a3 > 0.f ? a3 : 0.2f * a3;
        float w0 = __expf(fminf(a0, 60.f)), w1 = __expf(fminf(a1, 60.f));
        float w2 = __expf(fminf(a2, 60.f)), w3 = __expf(fminf(a3, 60.f));
        uint4v v0 = *(const uint4v*)(hu + (size_t)i0 * 256 + lane * 4);
        uint4v v1 = *(const uint4v*)(hu + (size_t)i1 * 256 + lane * 4);
        uint4v v2 = *(const uint4v*)(hu + (size_t)i2 * 256 + lane * 4);
        uint4v v3 = *(const uint4v*)(hu + (size_t)i3 * 256 + lane * 4);
        den += (w0 + w1) + (w2 + w3);
#pragma unroll
        for (int j = 0; j < 4; ++j) {
            acc[j].x += w0 * __uint_as_float(v0[j] << 16);
            acc[j].y += w0 * __uint_as_float(v0[j] & 0xffff0000u);
            acc[j].x += w1 * __uint_as_float(v1[j] << 16);
            acc[j].y += w1 * __uint_as_float(v1[j] & 0xffff0000u);
            acc[j].x += w2 * __uint_as_float(v2[j] << 16);
            acc[j].y += w2 * __uint_as_float(v2[j] & 0xffff0000u);
            acc[j].x += w3 * __uint_as_float(v3[j] << 16);
            acc[j].y += w3 * __uint_as_float(v3[j] & 0xffff0000u);
        }
    }
    for (; k < s1; ++k) {
        int i0 = csrc[k];
        float a = as_[(size_t)i0 * 8 + myh] + adn;
        a = a > 0.f ? a : 0.2f * a;
        float w = __expf(fminf(a, 60.f));
        uint4v v0 = *(const uint4v*)(hu + (size_t)i0 * 256 + lane * 4);
        den += w;
#pragma unroll
        for (int j = 0; j < 4; ++j) {
            acc[j].x += w * __uint_as_float(v0[j] << 16);
            acc[j].y += w * __uint_as_float(v0[j] & 0xffff0000u);
        }
    }
    float rden = 1.f / (den + 1e-16f);
    uint4v o;
#pragma unroll
    for (int j = 0; j < 4; ++j) {
        float vlo = acc[j].x * rden + bias[lane * 8 + 2 * j];
        float vhi = acc[j].y * rden + bias[lane * 8 + 2 * j + 1];
        vlo = vlo > 0.f ? vlo : 0.f;
        vhi = vhi > 0.f ? vhi : 0.f;
        o[j] = (unsigned)f2bf(vlo) | ((unsigned)f2bf(vhi) << 16);
    }
    *(uint4v*)(outp + (size_t)node * 512 + lane * 8) = o;
}

// ---------- K7: MFMA GEMM L2 (K=512) + attn2 dots ----------
__global__ __launch_bounds__(256) void gemm_l2_k512(const unsigned short* __restrict__ A,
                                                    const unsigned short* __restrict__ Bfrag,
                                                    unsigned short* __restrict__ Cbf,
                                                    int M,
                                                    const float* __restrict__ avs,
                                                    const float* __restrict__ avd,
                                                    float* __restrict__ as_,
                                                    float* __restrict__ ad_) {
    const int lane = threadIdx.x & 63;
    const int wave = threadIdx.x >> 6;
    const int l15 = lane & 15, l16 = lane >> 4;
    const long rowBase = (long)blockIdx.x * 128 + wave * 32;
    const bfrag8* bp = (const bfrag8*)Bfrag;

    f32x4 acc[2][4];
#pragma unroll
    for (int r = 0; r < 2; ++r)
#pragma unroll
        for (int c = 0; c < 4; ++c)
#pragma unroll
            for (int e = 0; e < 4; ++e) acc[r][c][e] = 0.f;

    long r0 = rowBase + l15;        if (r0 > M - 1) r0 = M - 1;
    long r1 = rowBase + 16 + l15;   if (r1 > M - 1) r1 = M - 1;
    const unsigned short* a0p = A + r0 * 512 + l16 * 8;
    const unsigned short* a1p = A + r1 * 512 + l16 * 8;

    for (int s = 0; s < 16; ++s) {
        bfrag8 a0 = *(const bfrag8*)(a0p + s * 32);
        bfrag8 a1 = *(const bfrag8*)(a1p + s * 32);
        bfrag8 bf0 = bp[(s * 4 + 0) * 64 + lane];
        bfrag8 bf1 = bp[(s * 4 + 1) * 64 + lane];
        bfrag8 bf2 = bp[(s * 4 + 2) * 64 + lane];
        bfrag8 bf3 = bp[(s * 4 + 3) * 64 + lane];
        acc[0][0] = __builtin_amdgcn_mfma_f32_16x16x32_bf16(a0, bf0, acc[0][0], 0, 0, 0);
        acc[1][0] = __builtin_amdgcn_mfma_f32_16x16x32_bf16(a1, bf0, acc[1][0], 0, 0, 0);
        acc[0][1] = __builtin_amdgcn_mfma_f32_16x16x32_bf16(a0, bf1, acc[0][1], 0, 0, 0);
        acc[1][1] = __builtin_amdgcn_mfma_f32_16x16x32_bf16(a1, bf1, acc[1][1], 0, 0, 0);
        acc[0][2] = __builtin_amdgcn_mfma_f32_16x16x32_bf16(a0, bf2, acc[0][2], 0, 0, 0);
        acc[1][2] = __builtin_amdgcn_mfma_f32_16x16x32_bf16(a1, bf2, acc[1][2], 0, 0, 0);
        acc[0][3] = __builtin_amdgcn_mfma_f32_16x16x32_bf16(a0, bf3, acc[0][3], 0, 0, 0);
        acc[1][3] = __builtin_amdgcn_mfma_f32_16x16x32_bf16(a1, bf3, acc[1][3], 0, 0, 0);
    }

    float avsv[4], avdv[4];
#pragma unroll
    for (int c = 0; c < 4; ++c) {
        avsv[c] = avs[c * 16 + l15];
        avdv[c] = avd[c * 16 + l15];
    }

#pragma unroll
    for (int r = 0; r < 2; ++r) {
#pragma unroll
        for (int reg = 0; reg < 4; ++reg) {
            long row = rowBase + r * 16 + l16 * 4 + reg;
            bool ok = row < M;
            float ps = 0.f, pd = 0.f;
#pragma unroll
            for (int c = 0; c < 4; ++c) {
                float v = acc[r][c][reg];
                if (ok) Cbf[row * 64 + c * 16 + l15] = f2bf(v);
                ps += v * avsv[c];
                pd += v * avdv[c];
            }
#pragma unroll
            for (int off = 1; off < 16; off <<= 1) {
                ps += __shfl_xor(ps, off);
                pd += __shfl_xor(pd, off);
            }
            if (l15 == 0 && ok) { as_[row] = ps; ad_[row] = pd; }
        }
    }
}

// ---------- K8: single-head gather -> f32 out ----------
__global__ __launch_bounds__(256) void gather1(const int* __restrict__ csrc,
                                               const int* __restrict__ rs,
                                               const float* __restrict__ as_,
                                               const float* __restrict__ ad_,
                                               const unsigned short* __restrict__ h,
                                               const float* __restrict__ bias,
                                               float* __restrict__ outp, int N) {
    int node = (int)((blockIdx.x * 256u + threadIdx.x) >> 6);
    int lane = threadIdx.x & 63;
    if (node >= N) return;
    int s0 = rs[node], s1 = rs[node + 1];
    float adn = ad_[node];
    float den = 0.f, acc = 0.f;
    int k = s0;
    for (; k + 4 <= s1; k += 4) {
        int i0 = csrc[k], i1 = csrc[k + 1], i2 = csrc[k + 2], i3 = csrc[k + 3];
        float a0 = as_[i0] + adn, a1 = as_[i1] + adn, a2 = as_[i2] + adn, a3 = as_[i3] + adn;
        a0 = a0 > 0.f ? a0 : 0.2f * a0;  a1 = a1 > 0.f ? a1 : 0.2f * a1;
        a2 = a2 > 0.f ? a2 : 0.2f * a2;  a3 = a3 > 0.f ? a3 : 0.2f * a3;
        float w0 = __expf(fminf(a0, 60.f)), w1 = __expf(fminf(a1, 60.f));
        float w2 = __expf(fminf(a2, 60.f)), w3 = __expf(fminf(a3, 60.f));
        float h0 = bf2f(h[(size_t)i0 * 64 + lane]);
        float h1 = bf2f(h[(size_t)i1 * 64 + lane]);
        float h2 = bf2f(h[(size_t)i2 * 64 + lane]);
        float h3 = bf2f(h[(size_t)i3 * 64 + lane]);
        den += (w0 + w1) + (w2 + w3);
        acc += w0 * h0;  acc += w1 * h1;  acc += w2 * h2;  acc += w3 * h3;
    }
    for (; k < s1; ++k) {
        int i0 = csrc[k];
        float a = as_[i0] + adn;
        a = a > 0.f ? a : 0.2f * a;
        float w = __expf(fminf(a, 60.f));
        den += w;
        acc += w * bf2f(h[(size_t)i0 * 64 + lane]);
    }
    float v = acc / (den + 1e-16f) + bias[lane];
    outp[(size_t)node * 64 + lane] = v > 0.f ? v : 0.f;
}

// ---------- K9: fused mean-pool + readout ----------
__global__ __launch_bounds__(256) void pool_readout(const float* __restrict__ h2,
                                                    const int* __restrict__ gstart,
                                                    const float* __restrict__ Wf,
                                                    const float* __restrict__ bf,
                                                    float* __restrict__ out, int G) {
    int g = (int)((blockIdx.x * 256u + threadIdx.x) >> 6);
    int lane = threadIdx.x & 63;
    if (g >= G) return;
    int s0 = gstart[g], s1 = gstart[g + 1];
    float acc = 0.f;
    int i = s0;
    for (; i + 2 <= s1; i += 2) {
        acc += h2[(size_t)i * 64 + lane];
        acc += h2[(size_t)(i + 1) * 64 + lane];
    }
    if (i < s1) acc += h2[(size_t)i * 64 + lane];
    float c = (float)(s1 - s0);
    c = c < 1.f ? 1.f : c;
    float v = acc / c * Wf[lane];
#pragma unroll
    for (int off = 32; off; off >>= 1) v += __shfl_xor(v, off);
    if (lane == 0) out[g] = v + bf[0];
}

extern "C" void kernel_launch(void* const* d_in, const int* in_sizes, int n_in,
                              void* d_out, int out_size, void* d_ws, size_t ws_size,
                              hipStream_t stream) {
    const float* x        = (const float*)d_in[0];
    const int*   ei       = (const int*)d_in[1];
    const int*   batch    = (const int*)d_in[2];
    const float* W1       = (const float*)d_in[3];
    const float* att_src1 = (const float*)d_in[4];
    const float* att_dst1 = (const float*)d_in[5];
    const float* b1       = (const float*)d_in[6];
    const float* W2       = (const float*)d_in[7];
    const float* att_src2 = (const float*)d_in[8];
    const float* att_dst2 = (const float*)d_in[9];
    const float* b2       = (const float*)d_in[10];
    const float* Wf       = (const float*)d_in[11];
    const float* bf       = (const float*)d_in[12];
    float* out = (float*)d_out;

    const int N = in_sizes[2];        // 100000
    const int E = in_sizes[1] / 2;    // 400000
    const int G = out_size;           // 4096

    const int nb = (N + SCAN_BLK - 1) / SCAN_BLK;
    const int nodeWaveGrid = (int)(((size_t)N * 64 + 255) / 256);
    const int edgeGrid = (E + N + 255) / 256;
    const int gemmGrid = (N + 127) / 128;

    // ---- workspace layout ----
    char* base = (char*)d_ws;
    size_t off = 0;
    auto alloc = [&](size_t bytes) { char* p = base + off; off += (bytes + 255) & ~255llu; return p; };
    unsigned short* wf1   = (unsigned short*)alloc(131072);
    unsigned short* wf2   = (unsigned short*)alloc(65536);
    float* as1            = (float*)alloc((size_t)N * 8 * 4);
    float* ad1            = (float*)alloc((size_t)N * 8 * 4);
    float* as2            = (float*)alloc((size_t)N * 4);
    float* ad2            = (float*)alloc((size_t)N * 4);
    int*   cnt_i          = (int*)alloc((size_t)N * 4);
    int*   rs             = (int*)alloc((size_t)(N + 1) * 4);
    int*   csrc           = (int*)alloc((size_t)(E + N) * 4);
    int*   bsum           = (int*)alloc(1024);
    int*   gstart         = (int*)alloc((size_t)(G + 1) * 4);
    unsigned short* x_bf  = (unsigned short*)alloc((size_t)N * 128 * 2);
    float* ob2            = (float*)x_bf;   // alias: x_bf dead before ob2 written
    unsigned short* h2bf  = (unsigned short*)alloc((size_t)N * 64 * 2);
    unsigned short* h1_bf = (unsigned short*)alloc((size_t)N * 512 * 2);
    unsigned short* ob1_bf= (unsigned short*)alloc((size_t)N * 512 * 2);
    (void)ws_size;

    // ---- K1: prologue (cvt + zero + weight pack + gstart) ----
    {
        int gsBlocks = (N + 256) / 256 + 1;         // covers i in [0, N]
        int grid = 1920 + gsBlocks;
        prologue<<<grid, 256, 0, stream>>>(x, x_bf, cnt_i, W1, W2, wf1, wf2,
                                           batch, gstart, rs, N, G, E);
    }

    // ---- K2: layer-1 GEMM (all 8 heads) + histogram tail ----
    {
        int gemmBlocks = gemmGrid * 8;
        gemm_l1_hist<<<gemmBlocks + edgeGrid, 256, 0, stream>>>(
            x_bf, wf1, h1_bf, N, att_src1, att_dst1, as1, ad1,
            gemmBlocks, gemmGrid, ei, cnt_i, E);
    }

    // ---- K3-K5: scan + scatter ----
    scan1<<<nb, 256, 0, stream>>>(cnt_i, rs, bsum, N);
    scan_fix<<<(N + 255) / 256, 256, 0, stream>>>(rs, bsum, N);
    scatter_cd<<<edgeGrid, 256, 0, stream>>>(ei, rs, cnt_i, csrc, E, N);

    // ---- K6: layer-1 aggregation (all heads) ----
    gather8<<<nodeWaveGrid, 256, 0, stream>>>(csrc, rs, as1, ad1, h1_bf, b1, ob1_bf, N);

    // ---- K7: layer-2 GEMM (K=512) + attn2 dots ----
    gemm_l2_k512<<<gemmGrid, 256, 0, stream>>>(ob1_bf, wf2, h2bf, N,
                                               att_src2, att_dst2, as2, ad2);

    // ---- K8: layer-2 aggregation ----
    gather1<<<nodeWaveGrid, 256, 0, stream>>>(csrc, rs, as2, ad2, h2bf, b2, ob2, N);

    // ---- K9: pool + readout ----
    pool_readout<<<(G * 64 + 255) / 256, 256, 0, stream>>>(ob2, gstart, Wf, bf, out, G);
}

// Round 10
// 282.429 us; speedup vs baseline: 1.2900x; 1.0363x over previous
//
#include <hip/hip_runtime.h>

typedef short bfrag8 __attribute__((ext_vector_type(8)));
typedef float f32x4 __attribute__((ext_vector_type(4)));
typedef unsigned int uint4v __attribute__((ext_vector_type(4)));

#define SCAN_BLK 2048

// ---------- helpers ----------
__device__ __forceinline__ unsigned short f2bf(float f) {
    unsigned u = __float_as_uint(f);
    u += 0x7fffu + ((u >> 16) & 1u);   // round-to-nearest-even
    return (unsigned short)(u >> 16);
}
__device__ __forceinline__ float bf2f(unsigned short s) {
    return __uint_as_float((unsigned)s << 16);
}
__device__ __forceinline__ bfrag8 pack8(float4 a, float4 b) {
    bfrag8 r;
    r[0] = (short)f2bf(a.x); r[1] = (short)f2bf(a.y);
    r[2] = (short)f2bf(a.z); r[3] = (short)f2bf(a.w);
    r[4] = (short)f2bf(b.x); r[5] = (short)f2bf(b.y);
    r[6] = (short)f2bf(b.z); r[7] = (short)f2bf(b.w);
    return r;
}

// ---------- K1: fused prologue ----------
// [0,512):   zero cnt (512*256 >= N)
// [512,768): pack W1 (256*256 = 65536 items)
// [768,896): pack W2 (128*256 = 32768 items)
// [896,...): gstart build + rs[N]=E+N
__global__ __launch_bounds__(256) void prologue(int* __restrict__ cnt,
                                                const float* __restrict__ W1,
                                                const float* __restrict__ W2,
                                                unsigned short* __restrict__ wf1,
                                                unsigned short* __restrict__ wf2,
                                                const int* __restrict__ batch,
                                                int* __restrict__ gstart,
                                                int* __restrict__ rs,
                                                int N, int G, int E) {
    const int b = blockIdx.x, t = threadIdx.x;
    if (b < 512) {
        int i = b * 256 + t;
        if (i < N) cnt[i] = 0;
    } else if (b < 768) {
        int i = (b - 512) * 256 + t;   // 65536 items
        int e = i & 7, l = (i >> 3) & 63, c = (i >> 9) & 3, s = (i >> 11) & 3, h = i >> 13;
        int k = s * 32 + (l >> 4) * 8 + e;
        int col = h * 64 + c * 16 + (l & 15);
        wf1[i] = f2bf(W1[k * 512 + col]);
    } else if (b < 896) {
        int i = (b - 768) * 256 + t;   // 32768 items
        int e = i & 7, l = (i >> 3) & 63, c = (i >> 9) & 3, s = i >> 11;
        int k = s * 32 + (l >> 4) * 8 + e;
        int col = c * 16 + (l & 15);
        wf2[i] = f2bf(W2[k * 64 + col]);
    } else {
        int i = (b - 896) * 256 + t;
        if (i == 0) rs[N] = E + N;
        if (i > N) return;
        if (i == N) {
            int p = batch[N - 1];
            for (int g = p + 1; g <= G; ++g) gstart[g] = N;
        } else {
            int bb = batch[i];
            int p = (i == 0) ? -1 : batch[i - 1];
            for (int g = p + 1; g <= bb; ++g) gstart[g] = i;
        }
    }
}

// ---------- K2: MFMA GEMM L1 (fp32 x in, head loop inside) + histogram tail ----------
__global__ __launch_bounds__(256) void gemm_l1_hist(const float* __restrict__ x,
                                                    const unsigned short* __restrict__ Bfrag,
                                                    unsigned short* __restrict__ Cbf,
                                                    int M,
                                                    const float* __restrict__ avs,
                                                    const float* __restrict__ avd,
                                                    float* __restrict__ as_,
                                                    float* __restrict__ ad_,
                                                    int gemmBlocks,
                                                    const int* __restrict__ ei,
                                                    int* __restrict__ cnt, int E) {
    const int b = blockIdx.x;
    if (b >= gemmBlocks) {
        int t = (b - gemmBlocks) * 256 + threadIdx.x;
        if (t < E + M) {
            int dst = (t < E) ? ei[E + t] : t - E;
            atomicAdd(cnt + dst, 1);
        }
        return;
    }
    const int lane = threadIdx.x & 63;
    const int wave = threadIdx.x >> 6;
    const int l15 = lane & 15, l16 = lane >> 4;
    const long rowBase = (long)b * 128 + wave * 32;

    long r0 = rowBase + l15;        if (r0 > M - 1) r0 = M - 1;
    long r1 = rowBase + 16 + l15;   if (r1 > M - 1) r1 = M - 1;

    // A fragments: read x fp32 once, convert in-register
    bfrag8 a0f[4], a1f[4];
#pragma unroll
    for (int s = 0; s < 4; ++s) {
        const float* p0 = x + r0 * 128 + s * 32 + l16 * 8;
        const float* p1 = x + r1 * 128 + s * 32 + l16 * 8;
        float4 u0 = *(const float4*)p0, u1 = *(const float4*)(p0 + 4);
        float4 v0 = *(const float4*)p1, v1 = *(const float4*)(p1 + 4);
        a0f[s] = pack8(u0, u1);
        a1f[s] = pack8(v0, v1);
    }

#pragma unroll 1
    for (int h = 0; h < 8; ++h) {
        bfrag8 bf[4][4];
        const bfrag8* bp = (const bfrag8*)(Bfrag + (size_t)h * 8192);
#pragma unroll
        for (int s = 0; s < 4; ++s)
#pragma unroll
            for (int c = 0; c < 4; ++c)
                bf[s][c] = bp[(s * 4 + c) * 64 + lane];

        f32x4 acc[2][4];
#pragma unroll
        for (int r = 0; r < 2; ++r)
#pragma unroll
            for (int c = 0; c < 4; ++c)
#pragma unroll
                for (int e = 0; e < 4; ++e) acc[r][c][e] = 0.f;

#pragma unroll
        for (int s = 0; s < 4; ++s) {
#pragma unroll
            for (int c = 0; c < 4; ++c) {
                acc[0][c] = __builtin_amdgcn_mfma_f32_16x16x32_bf16(a0f[s], bf[s][c], acc[0][c], 0, 0, 0);
                acc[1][c] = __builtin_amdgcn_mfma_f32_16x16x32_bf16(a1f[s], bf[s][c], acc[1][c], 0, 0, 0);
            }
        }

        float avsv[4], avdv[4];
#pragma unroll
        for (int c = 0; c < 4; ++c) {
            avsv[c] = avs[h * 64 + c * 16 + l15];
            avdv[c] = avd[h * 64 + c * 16 + l15];
        }

#pragma unroll
        for (int r = 0; r < 2; ++r) {
#pragma unroll
            for (int reg = 0; reg < 4; ++reg) {
                long row = rowBase + r * 16 + l16 * 4 + reg;
                bool ok = row < M;
                float ps = 0.f, pd = 0.f;
#pragma unroll
                for (int c = 0; c < 4; ++c) {
                    float v = acc[r][c][reg];
                    if (ok) Cbf[row * 512 + h * 64 + c * 16 + l15] = f2bf(v);
                    ps += v * avsv[c];
                    pd += v * avdv[c];
                }
#pragma unroll
                for (int off = 1; off < 16; off <<= 1) {
                    ps += __shfl_xor(ps, off);
                    pd += __shfl_xor(pd, off);
                }
                if (l15 == 0 && ok) {
                    as_[row * 8 + h] = ps;
                    ad_[row * 8 + h] = pd;
                }
            }
        }
    }
}

// ---------- K3: per-chunk scan ----------
__global__ __launch_bounds__(256) void scan1(const int* __restrict__ cnt,
                                             int* __restrict__ rs,
                                             int* __restrict__ bsum, int N) {
    __shared__ int lds[256];
    int base = blockIdx.x * SCAN_BLK;
    int vals[8];
    int tsum = 0;
    int idx0 = base + threadIdx.x * 8;
#pragma unroll
    for (int j = 0; j < 8; ++j) {
        int i = idx0 + j;
        int v = (i < N) ? cnt[i] : 0;
        vals[j] = tsum;
        tsum += v;
    }
    lds[threadIdx.x] = tsum;
    __syncthreads();
    for (int off = 1; off < 256; off <<= 1) {
        int v = lds[threadIdx.x];
        int u = (threadIdx.x >= (unsigned)off) ? lds[threadIdx.x - off] : 0;
        __syncthreads();
        lds[threadIdx.x] = v + u;
        __syncthreads();
    }
    int texcl = (threadIdx.x == 0) ? 0 : lds[threadIdx.x - 1];
#pragma unroll
    for (int j = 0; j < 8; ++j) {
        int i = idx0 + j;
        if (i < N) rs[i] = texcl + vals[j];
    }
    if (threadIdx.x == 255) bsum[blockIdx.x] = lds[255];
}

// ---------- K4: scan fixup ----------
__global__ __launch_bounds__(256) void scan_fix(int* __restrict__ rs,
                                                const int* __restrict__ bsum, int N) {
    __shared__ int sprefix;
    int b = blockIdx.x;
    int i = b * 256 + threadIdx.x;
    int chunk = (b * 256) / SCAN_BLK;
    if (threadIdx.x == 0) {
        int p = 0;
        for (int k = 0; k < chunk; ++k) p += bsum[k];
        sprefix = p;
    }
    __syncthreads();
    if (i < N) rs[i] += sprefix;
}

// ---------- K5: scatter via count-down ----------
__global__ __launch_bounds__(256) void scatter_cd(const int* __restrict__ ei,
                                                  const int* __restrict__ rs,
                                                  int* __restrict__ cnt,
                                                  int* __restrict__ csrc, int E, int N) {
    int t = (int)(blockIdx.x * 256u + threadIdx.x);
    if (t >= E + N) return;
    int src, dst;
    if (t < E) { src = ei[t]; dst = ei[E + t]; } else { src = dst = t - E; }
    int pos = rs[dst] + atomicSub(cnt + dst, 1) - 1;
    csrc[pos] = src;
}

// ---------- K6: gather over all 8 heads (masked 4-wide batches, no serial tail) ----------
__global__ __launch_bounds__(256) void gather8(const int* __restrict__ csrc,
                                               const int* __restrict__ rs,
                                               const float* __restrict__ as_,  // [N][8]
                                               const float* __restrict__ ad_,  // [N][8]
                                               const unsigned short* __restrict__ h, // [N][512]
                                               const float* __restrict__ bias,      // [512]
                                               unsigned short* __restrict__ outp,   // [N][512]
                                               int N) {
    int node = (int)((blockIdx.x * 256u + threadIdx.x) >> 6);
    int lane = threadIdx.x & 63;
    if (node >= N) return;
    int myh = lane >> 3;
    int s0 = rs[node], s1 = rs[node + 1];
    float adn = ad_[(size_t)node * 8 + myh];
    float den = 0.f;
    float2 acc[4] = {};
    const unsigned* hu = (const unsigned*)h;
    for (int k = s0; k < s1; k += 4) {
        int k1 = k + 1 < s1 ? k + 1 : s0;
        int k2 = k + 2 < s1 ? k + 2 : s0;
        int k3 = k + 3 < s1 ? k + 3 : s0;
        bool m1 = k + 1 < s1, m2 = k + 2 < s1, m3 = k + 3 < s1;
        int i0 = csrc[k], i1 = csrc[k1], i2 = csrc[k2], i3 = csrc[k3];
        float a0 = as_[(size_t)i0 * 8 + myh] + adn;
        float a1 = as_[(size_t)i1 * 8 + myh] + adn;
        float a2 = as_[(size_t)i2 * 8 + myh] + adn;
        float a3 = as_[(size_t)i3 * 8 + myh] + adn;
        a0 = a0 > 0.f ? a0 : 0.2f * a0;  a1 = a1 > 0.f ? a1 : 0.2f * a1;
        a2 = a2 > 0.f ? a2 : 0.2f * a2;  a3 = a3 > 0.f ? a3 : 0.2f * a3;
        float w0 = __expf(fminf(a0, 60.f));
        float w1 = m1 ? __expf(fminf(a1, 60.f)) : 0.f;
        float w2 = m2 ? __expf(fminf(a2, 60.f)) : 0.f;
        float w3 = m3 ? __expf(fminf(a3, 60.f)) : 0.f;
        uint4v v0 = *(const uint4v*)(hu + (size_t)i0 * 256 + lane * 4);
        uint4v v1 = *(const uint4v*)(hu + (size_t)i1 * 256 + lane * 4);
        uint4v v2 = *(const uint4v*)(hu + (size_t)i2 * 256 + lane * 4);
        uint4v v3 = *(const uint4v*)(hu + (size_t)i3 * 256 + lane * 4);
        den += (w0 + w1) + (w2 + w3);
#pragma unroll
        for (int j = 0; j < 4; ++j) {
            acc[j].x += w0 * __uint_as_float(v0[j] << 16);
            acc[j].y += w0 * __uint_as_float(v0[j] & 0xffff0000u);
            acc[j].x += w1 * __uint_as_float(v1[j] << 16);
            acc[j].y += w1 * __uint_as_float(v1[j] & 0xffff0000u);
            acc[j].x += w2 * __uint_as_float(v2[j] << 16);
            acc[j].y += w2 * __uint_as_float(v2[j] & 0xffff0000u);
            acc[j].x += w3 * __uint_as_float(v3[j] << 16);
            acc[j].y += w3 * __uint_as_float(v3[j] & 0xffff0000u);
        }
    }
    float rden = 1.f / (den + 1e-16f);
    uint4v o;
#pragma unroll
    for (int j = 0; j < 4; ++j) {
        float vlo = acc[j].x * rden + bias[lane * 8 + 2 * j];
        float vhi = acc[j].y * rden + bias[lane * 8 + 2 * j + 1];
        vlo = vlo > 0.f ? vlo : 0.f;
        vhi = vhi > 0.f ? vhi : 0.f;
        o[j] = (unsigned)f2bf(vlo) | ((unsigned)f2bf(vhi) << 16);
    }
    *(uint4v*)(outp + (size_t)node * 512 + lane * 8) = o;
}

// ---------- K7: MFMA GEMM L2 (K=512) + attn2 dots ----------
__global__ __launch_bounds__(256) void gemm_l2_k512(const unsigned short* __restrict__ A,
                                                    const unsigned short* __restrict__ Bfrag,
                                                    unsigned short* __restrict__ Cbf,
                                                    int M,
                                                    const float* __restrict__ avs,
                                                    const float* __restrict__ avd,
                                                    float* __restrict__ as_,
                                                    float* __restrict__ ad_) {
    const int lane = threadIdx.x & 63;
    const int wave = threadIdx.x >> 6;
    const int l15 = lane & 15, l16 = lane >> 4;
    const long rowBase = (long)blockIdx.x * 128 + wave * 32;
    const bfrag8* bp = (const bfrag8*)Bfrag;

    f32x4 acc[2][4];
#pragma unroll
    for (int r = 0; r < 2; ++r)
#pragma unroll
        for (int c = 0; c < 4; ++c)
#pragma unroll
            for (int e = 0; e < 4; ++e) acc[r][c][e] = 0.f;

    long r0 = rowBase + l15;        if (r0 > M - 1) r0 = M - 1;
    long r1 = rowBase + 16 + l15;   if (r1 > M - 1) r1 = M - 1;
    const unsigned short* a0p = A + r0 * 512 + l16 * 8;
    const unsigned short* a1p = A + r1 * 512 + l16 * 8;

    for (int s = 0; s < 16; ++s) {
        bfrag8 a0 = *(const bfrag8*)(a0p + s * 32);
        bfrag8 a1 = *(const bfrag8*)(a1p + s * 32);
        bfrag8 bf0 = bp[(s * 4 + 0) * 64 + lane];
        bfrag8 bf1 = bp[(s * 4 + 1) * 64 + lane];
        bfrag8 bf2 = bp[(s * 4 + 2) * 64 + lane];
        bfrag8 bf3 = bp[(s * 4 + 3) * 64 + lane];
        acc[0][0] = __builtin_amdgcn_mfma_f32_16x16x32_bf16(a0, bf0, acc[0][0], 0, 0, 0);
        acc[1][0] = __builtin_amdgcn_mfma_f32_16x16x32_bf16(a1, bf0, acc[1][0], 0, 0, 0);
        acc[0][1] = __builtin_amdgcn_mfma_f32_16x16x32_bf16(a0, bf1, acc[0][1], 0, 0, 0);
        acc[1][1] = __builtin_amdgcn_mfma_f32_16x16x32_bf16(a1, bf1, acc[1][1], 0, 0, 0);
        acc[0][2] = __builtin_amdgcn_mfma_f32_16x16x32_bf16(a0, bf2, acc[0][2], 0, 0, 0);
        acc[1][2] = __builtin_amdgcn_mfma_f32_16x16x32_bf16(a1, bf2, acc[1][2], 0, 0, 0);
        acc[0][3] = __builtin_amdgcn_mfma_f32_16x16x32_bf16(a0, bf3, acc[0][3], 0, 0, 0);
        acc[1][3] = __builtin_amdgcn_mfma_f32_16x16x32_bf16(a1, bf3, acc[1][3], 0, 0, 0);
    }

    float avsv[4], avdv[4];
#pragma unroll
    for (int c = 0; c < 4; ++c) {
        avsv[c] = avs[c * 16 + l15];
        avdv[c] = avd[c * 16 + l15];
    }

#pragma unroll
    for (int r = 0; r < 2; ++r) {
#pragma unroll
        for (int reg = 0; reg < 4; ++reg) {
            long row = rowBase + r * 16 + l16 * 4 + reg;
            bool ok = row < M;
            float ps = 0.f, pd = 0.f;
#pragma unroll
            for (int c = 0; c < 4; ++c) {
                float v = acc[r][c][reg];
                if (ok) Cbf[row * 64 + c * 16 + l15] = f2bf(v);
                ps += v * avsv[c];
                pd += v * avdv[c];
            }
#pragma unroll
            for (int off = 1; off < 16; off <<= 1) {
                ps += __shfl_xor(ps, off);
                pd += __shfl_xor(pd, off);
            }
            if (l15 == 0 && ok) { as_[row] = ps; ad_[row] = pd; }
        }
    }
}

// ---------- K8: single-head gather (masked 4-wide batches) -> f32 out ----------
__global__ __launch_bounds__(256) void gather1(const int* __restrict__ csrc,
                                               const int* __restrict__ rs,
                                               const float* __restrict__ as_,
                                               const float* __restrict__ ad_,
                                               const unsigned short* __restrict__ h,
                                               const float* __restrict__ bias,
                                               float* __restrict__ outp, int N) {
    int node = (int)((blockIdx.x * 256u + threadIdx.x) >> 6);
    int lane = threadIdx.x & 63;
    if (node >= N) return;
    int s0 = rs[node], s1 = rs[node + 1];
    float adn = ad_[node];
    float den = 0.f, acc = 0.f;
    for (int k = s0; k < s1; k += 4) {
        int k1 = k + 1 < s1 ? k + 1 : s0;
        int k2 = k + 2 < s1 ? k + 2 : s0;
        int k3 = k + 3 < s1 ? k + 3 : s0;
        bool m1 = k + 1 < s1, m2 = k + 2 < s1, m3 = k + 3 < s1;
        int i0 = csrc[k], i1 = csrc[k1], i2 = csrc[k2], i3 = csrc[k3];
        float a0 = as_[i0] + adn, a1 = as_[i1] + adn, a2 = as_[i2] + adn, a3 = as_[i3] + adn;
        a0 = a0 > 0.f ? a0 : 0.2f * a0;  a1 = a1 > 0.f ? a1 : 0.2f * a1;
        a2 = a2 > 0.f ? a2 : 0.2f * a2;  a3 = a3 > 0.f ? a3 : 0.2f * a3;
        float w0 = __expf(fminf(a0, 60.f));
        float w1 = m1 ? __expf(fminf(a1, 60.f)) : 0.f;
        float w2 = m2 ? __expf(fminf(a2, 60.f)) : 0.f;
        float w3 = m3 ? __expf(fminf(a3, 60.f)) : 0.f;
        float h0 = bf2f(h[(size_t)i0 * 64 + lane]);
        float h1 = bf2f(h[(size_t)i1 * 64 + lane]);
        float h2 = bf2f(h[(size_t)i2 * 64 + lane]);
        float h3 = bf2f(h[(size_t)i3 * 64 + lane]);
        den += (w0 + w1) + (w2 + w3);
        acc += w0 * h0;  acc += w1 * h1;  acc += w2 * h2;  acc += w3 * h3;
    }
    float v = acc / (den + 1e-16f) + bias[lane];
    outp[(size_t)node * 64 + lane] = v > 0.f ? v : 0.f;
}

// ---------- K9: fused mean-pool + readout ----------
__global__ __launch_bounds__(256) void pool_readout(const float* __restrict__ h2,
                                                    const int* __restrict__ gstart,
                                                    const float* __restrict__ Wf,
                                                    const float* __restrict__ bf,
                                                    float* __restrict__ out, int G) {
    int g = (int)((blockIdx.x * 256u + threadIdx.x) >> 6);
    int lane = threadIdx.x & 63;
    if (g >= G) return;
    int s0 = gstart[g], s1 = gstart[g + 1];
    float acc = 0.f;
    int i = s0;
    for (; i + 2 <= s1; i += 2) {
        acc += h2[(size_t)i * 64 + lane];
        acc += h2[(size_t)(i + 1) * 64 + lane];
    }
    if (i < s1) acc += h2[(size_t)i * 64 + lane];
    float c = (float)(s1 - s0);
    c = c < 1.f ? 1.f : c;
    float v = acc / c * Wf[lane];
#pragma unroll
    for (int off = 32; off; off >>= 1) v += __shfl_xor(v, off);
    if (lane == 0) out[g] = v + bf[0];
}

extern "C" void kernel_launch(void* const* d_in, const int* in_sizes, int n_in,
                              void* d_out, int out_size, void* d_ws, size_t ws_size,
                              hipStream_t stream) {
    const float* x        = (const float*)d_in[0];
    const int*   ei       = (const int*)d_in[1];
    const int*   batch    = (const int*)d_in[2];
    const float* W1       = (const float*)d_in[3];
    const float* att_src1 = (const float*)d_in[4];
    const float* att_dst1 = (const float*)d_in[5];
    const float* b1       = (const float*)d_in[6];
    const float* W2       = (const float*)d_in[7];
    const float* att_src2 = (const float*)d_in[8];
    const float* att_dst2 = (const float*)d_in[9];
    const float* b2       = (const float*)d_in[10];
    const float* Wf       = (const float*)d_in[11];
    const float* bf       = (const float*)d_in[12];
    float* out = (float*)d_out;

    const int N = in_sizes[2];        // 100000
    const int E = in_sizes[1] / 2;    // 400000
    const int G = out_size;           // 4096

    const int nb = (N + SCAN_BLK - 1) / SCAN_BLK;
    const int nodeWaveGrid = (int)(((size_t)N * 64 + 255) / 256);
    const int edgeGrid = (E + N + 255) / 256;
    const int gemmGrid = (N + 127) / 128;

    // ---- workspace layout ----
    char* base = (char*)d_ws;
    size_t off = 0;
    auto alloc = [&](size_t bytes) { char* p = base + off; off += (bytes + 255) & ~255llu; return p; };
    unsigned short* wf1   = (unsigned short*)alloc(131072);
    unsigned short* wf2   = (unsigned short*)alloc(65536);
    float* as1            = (float*)alloc((size_t)N * 8 * 4);
    float* ad1            = (float*)alloc((size_t)N * 8 * 4);
    float* as2            = (float*)alloc((size_t)N * 4);
    float* ad2            = (float*)alloc((size_t)N * 4);
    int*   cnt_i          = (int*)alloc((size_t)N * 4);
    int*   rs             = (int*)alloc((size_t)(N + 1) * 4);
    int*   csrc           = (int*)alloc((size_t)(E + N) * 4);
    int*   bsum           = (int*)alloc(1024);
    int*   gstart         = (int*)alloc((size_t)(G + 1) * 4);
    float* ob2            = (float*)alloc((size_t)N * 64 * 4);
    unsigned short* h2bf  = (unsigned short*)alloc((size_t)N * 64 * 2);
    unsigned short* h1_bf = (unsigned short*)alloc((size_t)N * 512 * 2);
    unsigned short* ob1_bf= (unsigned short*)alloc((size_t)N * 512 * 2);
    (void)ws_size;

    // ---- K1: prologue (zero + weight pack + gstart) ----
    {
        int gsBlocks = (N + 256) / 256 + 1;         // covers i in [0, N]
        prologue<<<896 + gsBlocks, 256, 0, stream>>>(cnt_i, W1, W2, wf1, wf2,
                                                     batch, gstart, rs, N, G, E);
    }

    // ---- K2: layer-1 GEMM (fp32 x, all heads inside) + histogram tail ----
    gemm_l1_hist<<<gemmGrid + edgeGrid, 256, 0, stream>>>(
        x, wf1, h1_bf, N, att_src1, att_dst1, as1, ad1,
        gemmGrid, ei, cnt_i, E);

    // ---- K3-K5: scan + scatter ----
    scan1<<<nb, 256, 0, stream>>>(cnt_i, rs, bsum, N);
    scan_fix<<<(N + 255) / 256, 256, 0, stream>>>(rs, bsum, N);
    scatter_cd<<<edgeGrid, 256, 0, stream>>>(ei, rs, cnt_i, csrc, E, N);

    // ---- K6: layer-1 aggregation (all heads) ----
    gather8<<<nodeWaveGrid, 256, 0, stream>>>(csrc, rs, as1, ad1, h1_bf, b1, ob1_bf, N);

    // ---- K7: layer-2 GEMM (K=512) + attn2 dots ----
    gemm_l2_k512<<<gemmGrid, 256, 0, stream>>>(ob1_bf, wf2, h2bf, N,
                                               att_src2, att_dst2, as2, ad2);

    // ---- K8: layer-2 aggregation ----
    gather1<<<nodeWaveGrid, 256, 0, stream>>>(csrc, rs, as2, ad2, h2bf, b2, ob2, N);

    // ---- K9: pool + readout ----
    pool_readout<<<(G * 64 + 255) / 256, 256, 0, stream>>>(ob2, gstart, Wf, bf, out, G);
}